// Round 1
// baseline (1187.339 us; speedup 1.0000x reference)
//
#include <hip/hip_runtime.h>
#include <math.h>

// Problem constants
#define Bsz 2
#define Nseq 2048
#define Edim 1024
#define HQ 16
#define Gsz 4
#define HK 4
#define Dh 64
#define ROWS (Bsz * Nseq)   // 4096

// ---------------- fp32 tiled GEMM: C(MxN) = A(MxK) @ B(KxN), all row-major ---
#define BM 64
#define BN 64
#define BK 16

__global__ __launch_bounds__(256) void sgemm64(const float* __restrict__ A,
                                               const float* __restrict__ B,
                                               float* __restrict__ C,
                                               int M, int N, int K) {
    __shared__ float As[BK][BM + 1];   // transposed store, +1 pad kills write conflicts
    __shared__ float Bs[BK][BN];

    const int tid = threadIdx.x;
    const int tx = tid & 15;
    const int ty = tid >> 4;
    const int row0 = blockIdx.y * BM;
    const int col0 = blockIdx.x * BN;

    float acc[4][4] = {};

    for (int k0 = 0; k0 < K; k0 += BK) {
        // A tile: 64 rows x 16 k  (1024 elems, 4 per thread)
#pragma unroll
        for (int i = 0; i < 4; ++i) {
            int idx = i * 256 + tid;
            int r  = idx >> 4;        // /16
            int kk = idx & 15;
            As[kk][r] = A[(size_t)(row0 + r) * K + k0 + kk];
        }
        // B tile: 16 k x 64 cols
#pragma unroll
        for (int i = 0; i < 4; ++i) {
            int idx = i * 256 + tid;
            int kk = idx >> 6;        // /64
            int c  = idx & 63;
            Bs[kk][c] = B[(size_t)(k0 + kk) * N + col0 + c];
        }
        __syncthreads();

#pragma unroll
        for (int kk = 0; kk < BK; ++kk) {
            float a[4], b[4];
#pragma unroll
            for (int i = 0; i < 4; ++i) a[i] = As[kk][ty * 4 + i];
#pragma unroll
            for (int j = 0; j < 4; ++j) b[j] = Bs[kk][tx * 4 + j];
#pragma unroll
            for (int i = 0; i < 4; ++i)
#pragma unroll
                for (int j = 0; j < 4; ++j)
                    acc[i][j] = fmaf(a[i], b[j], acc[i][j]);
        }
        __syncthreads();
    }

#pragma unroll
    for (int i = 0; i < 4; ++i)
#pragma unroll
        for (int j = 0; j < 4; ++j)
            C[(size_t)(row0 + ty * 4 + i) * N + col0 + tx * 4 + j] = acc[i][j];
}

// ---------------- flash-style causal GQA attention (fp32) ---------------------
// grid: (N/64, HQ, B); block: 256 threads (16x16), each owns 4x4 of the 64x64 tile.
__global__ __launch_bounds__(256) void attn64(const float* __restrict__ q,
                                              const float* __restrict__ k,
                                              const float* __restrict__ v,
                                              float* __restrict__ o) {
    __shared__ float Qs[64][65];
    __shared__ float KVs[64][65];   // time-shared: K during scores, V during PV
    __shared__ float Ps[64][65];

    const int tid = threadIdx.x;
    const int tx = tid & 15;
    const int ty = tid >> 4;
    const int rowTile = blockIdx.x;        // 0..31
    const int hq = blockIdx.y;             // 0..15
    const int b  = blockIdx.z;             // 0..1
    const int hk = hq >> 2;                // hq / G
    const int r0 = rowTile * 64;
    const float scale = 0.125f;            // 1/sqrt(64)

    // load Q tile: rows r0..r0+63 of channel block hq*64..+63
#pragma unroll
    for (int i = 0; i < 16; ++i) {
        int idx = i * 256 + tid;
        int r = idx >> 6, d = idx & 63;
        Qs[r][d] = q[(size_t)(b * Nseq + r0 + r) * Edim + hq * Dh + d];
    }

    float m[4], l[4], acc[4][4];
#pragma unroll
    for (int i = 0; i < 4; ++i) {
        m[i] = -INFINITY;
        l[i] = 0.0f;
#pragma unroll
        for (int j = 0; j < 4; ++j) acc[i][j] = 0.0f;
    }

    for (int t = 0; t <= rowTile; ++t) {
        const int s0 = t * 64;
        __syncthreads();   // previous PV reads of KVs done
        // K tile
#pragma unroll
        for (int i = 0; i < 16; ++i) {
            int idx = i * 256 + tid;
            int s = idx >> 6, d = idx & 63;
            KVs[s][d] = k[(size_t)(b * Nseq + s0 + s) * (HK * Dh) + hk * Dh + d];
        }
        __syncthreads();

        // scores S = Q K^T (4x4 per thread)
        float sreg[4][4] = {};
        for (int d = 0; d < 64; ++d) {
            float qa[4], kb[4];
#pragma unroll
            for (int i = 0; i < 4; ++i) qa[i] = Qs[ty * 4 + i][d];
#pragma unroll
            for (int j = 0; j < 4; ++j) kb[j] = KVs[tx * 4 + j][d];
#pragma unroll
            for (int i = 0; i < 4; ++i)
#pragma unroll
                for (int j = 0; j < 4; ++j)
                    sreg[i][j] = fmaf(qa[i], kb[j], sreg[i][j]);
        }

        // scale + causal mask
        const bool diag = (t == rowTile);
#pragma unroll
        for (int i = 0; i < 4; ++i)
#pragma unroll
            for (int j = 0; j < 4; ++j) {
                float sv = sreg[i][j] * scale;
                if (diag) {
                    int gr = ty * 4 + i;       // local row == global offset within tile
                    int gc = tx * 4 + j;
                    if (gc > gr) sv = -INFINITY;
                }
                sreg[i][j] = sv;
            }

        // online softmax per row (reduce across the 16-lane tx group)
#pragma unroll
        for (int i = 0; i < 4; ++i) {
            float mx = fmaxf(fmaxf(sreg[i][0], sreg[i][1]), fmaxf(sreg[i][2], sreg[i][3]));
#pragma unroll
            for (int off = 1; off < 16; off <<= 1)
                mx = fmaxf(mx, __shfl_xor(mx, off, 64));
            float mnew = fmaxf(m[i], mx);
            float alpha = __expf(m[i] - mnew);   // expf(-inf)=0 on first tile
            float rsum = 0.0f;
#pragma unroll
            for (int j = 0; j < 4; ++j) {
                float p = __expf(sreg[i][j] - mnew);
                sreg[i][j] = p;
                rsum += p;
            }
#pragma unroll
            for (int off = 1; off < 16; off <<= 1)
                rsum += __shfl_xor(rsum, off, 64);
            m[i] = mnew;
            l[i] = l[i] * alpha + rsum;
#pragma unroll
            for (int j = 0; j < 4; ++j) acc[i][j] *= alpha;
        }

        // stage P, then load V over K
#pragma unroll
        for (int i = 0; i < 4; ++i)
#pragma unroll
            for (int j = 0; j < 4; ++j)
                Ps[ty * 4 + i][tx * 4 + j] = sreg[i][j];
        __syncthreads();   // K reads done + P fully written
#pragma unroll
        for (int i = 0; i < 16; ++i) {
            int idx = i * 256 + tid;
            int s = idx >> 6, d = idx & 63;
            KVs[s][d] = v[(size_t)(b * Nseq + s0 + s) * (HK * Dh) + hk * Dh + d];
        }
        __syncthreads();

        // O += P @ V
        for (int jj = 0; jj < 64; ++jj) {
            float pa[4], vb[4];
#pragma unroll
            for (int i = 0; i < 4; ++i) pa[i] = Ps[ty * 4 + i][jj];
#pragma unroll
            for (int j = 0; j < 4; ++j) vb[j] = KVs[jj][tx * 4 + j];
#pragma unroll
            for (int i = 0; i < 4; ++i)
#pragma unroll
                for (int j = 0; j < 4; ++j)
                    acc[i][j] = fmaf(pa[i], vb[j], acc[i][j]);
        }
    }

    // epilogue: normalize and write (channel order == hq*D + d, matches reference)
#pragma unroll
    for (int i = 0; i < 4; ++i) {
        float inv = 1.0f / l[i];
#pragma unroll
        for (int j = 0; j < 4; ++j)
            o[(size_t)(b * Nseq + r0 + ty * 4 + i) * Edim + hq * Dh + tx * 4 + j] =
                acc[i][j] * inv;
    }
}

// ---------------- launch ------------------------------------------------------
extern "C" void kernel_launch(void* const* d_in, const int* in_sizes, int n_in,
                              void* d_out, int out_size, void* d_ws, size_t ws_size,
                              hipStream_t stream) {
    const float* x  = (const float*)d_in[0];
    const float* Wq = (const float*)d_in[1];
    const float* Wk = (const float*)d_in[2];
    const float* Wv = (const float*)d_in[3];
    const float* Wo = (const float*)d_in[4];
    float* out = (float*)d_out;

    float* q  = (float*)d_ws;                       // ROWS x 1024
    float* kk = q  + (size_t)ROWS * Edim;           // ROWS x 256
    float* vv = kk + (size_t)ROWS * (HK * Dh);      // ROWS x 256
    float* at = vv + (size_t)ROWS * (HK * Dh);      // ROWS x 1024

    // projections
    sgemm64<<<dim3(Edim / BN, ROWS / BM), 256, 0, stream>>>(x, Wq, q, ROWS, Edim, Edim);
    sgemm64<<<dim3((HK * Dh) / BN, ROWS / BM), 256, 0, stream>>>(x, Wk, kk, ROWS, HK * Dh, Edim);
    sgemm64<<<dim3((HK * Dh) / BN, ROWS / BM), 256, 0, stream>>>(x, Wv, vv, ROWS, HK * Dh, Edim);

    // attention
    attn64<<<dim3(Nseq / 64, HQ, Bsz), 256, 0, stream>>>(q, kk, vv, at);

    // output projection
    sgemm64<<<dim3(Edim / BN, ROWS / BM), 256, 0, stream>>>(at, Wo, out, ROWS, Edim, Edim);
}

// Round 3
// 294.728 us; speedup vs baseline: 4.0286x; 4.0286x over previous
//
#include <hip/hip_runtime.h>
#include <math.h>

// Problem constants
#define Bsz 2
#define Nseq 2048
#define Edim 1024
#define HQ 16
#define HK 4
#define Dh 64
#define ROWS (Bsz * Nseq)          // 4096
#define QKVW 1536                  // q(1024) | k(256) | v(256)

typedef __attribute__((ext_vector_type(8))) short short8;
typedef __attribute__((ext_vector_type(4))) float f32x4;

__device__ __forceinline__ ushort f2bf(float f) {
    union { float f; unsigned u; } v; v.f = f;
    unsigned r = (v.u + 0x7FFFu + ((v.u >> 16) & 1u)) >> 16;
    return (ushort)r;
}

// async global->LDS, 16B per lane; lds base must be wave-uniform
__device__ __forceinline__ void gld16(const void* g, void* l) {
    __builtin_amdgcn_global_load_lds(
        (const __attribute__((address_space(1))) unsigned*)g,
        (__attribute__((address_space(3))) unsigned*)l, 16, 0, 0);
}

// ---------------- prep: cast x to bf16 ---------------------------------------
__global__ __launch_bounds__(256) void castx(const float* __restrict__ x,
                                             ushort* __restrict__ xb) {
    size_t i = ((size_t)blockIdx.x * 256 + threadIdx.x) * 8;
    float4 a = *(const float4*)(x + i);
    float4 c = *(const float4*)(x + i + 4);
    short8 v;
    v[0] = f2bf(a.x); v[1] = f2bf(a.y); v[2] = f2bf(a.z); v[3] = f2bf(a.w);
    v[4] = f2bf(c.x); v[5] = f2bf(c.y); v[6] = f2bf(c.z); v[7] = f2bf(c.w);
    *(short8*)(xb + i) = v;
}

// ---------------- prep: transpose-cast W [K][N] fp32 -> WT [N][K] bf16 -------
__global__ __launch_bounds__(256) void tcast(const float* __restrict__ src,
                                             ushort* __restrict__ dst,
                                             int N, int Krows) {
    __shared__ float tle[32][33];
    int j0 = blockIdx.x * 32, k0 = blockIdx.y * 32;
    int tx = threadIdx.x, ty = threadIdx.y;
#pragma unroll
    for (int i = ty; i < 32; i += 8)
        tle[i][tx] = src[(size_t)(k0 + i) * N + j0 + tx];
    __syncthreads();
#pragma unroll
    for (int i = ty; i < 32; i += 8)
        dst[(size_t)(j0 + i) * Krows + k0 + tx] = f2bf(tle[tx][i]);
}

// ---------------- bf16 MFMA GEMM: C[M][N] = A[M][K] @ BT[N][K]^T -------------
// 128x128 tile, BK=32, 256 threads (4 waves), global_load_lds staging,
// LDS layout [g=k/8][row][16B] so A/B fragments are contiguous ds_read_b128.
template<int WRITE_BF16>
__global__ __launch_bounds__(256) void gemm_bt(const ushort* __restrict__ A,
                                               const ushort* __restrict__ BT,
                                               void* __restrict__ Cout,
                                               int M, int N, int K) {
    __shared__ __attribute__((aligned(16))) ushort As[2][4][128][8];
    __shared__ __attribute__((aligned(16))) ushort Bs[2][4][128][8];
    const int tid = threadIdx.x;
    const int l = tid & 63, li = l & 15, lg = l >> 4;
    const int w = tid >> 6;
    const int wr = w >> 1, wc = w & 1;
    const int row0 = blockIdx.y * 128, col0 = blockIdx.x * 128;

    f32x4 acc[4][4];
#pragma unroll
    for (int i = 0; i < 4; ++i)
#pragma unroll
        for (int j = 0; j < 4; ++j) {
            acc[i][j][0] = 0.f; acc[i][j][1] = 0.f;
            acc[i][j][2] = 0.f; acc[i][j][3] = 0.f;
        }

    const int nk = K >> 5;

#define G_STAGE(buf, kk)                                                        \
    {                                                                           \
        int k0 = (kk) << 5;                                                     \
        _Pragma("unroll")                                                       \
        for (int i = 0; i < 2; ++i) {                                           \
            int id = w + i * 4;                                                 \
            int g = id >> 1, h = id & 1;                                        \
            gld16(A + (size_t)(row0 + h * 64 + l) * K + k0 + g * 8,             \
                  &As[buf][g][h * 64][0]);                                      \
            gld16(BT + (size_t)(col0 + h * 64 + l) * K + k0 + g * 8,            \
                  &Bs[buf][g][h * 64][0]);                                      \
        }                                                                       \
    }

    G_STAGE(0, 0);
    __syncthreads();
    int buf = 0;
    for (int kk = 0; kk < nk; ++kk) {
        if (kk + 1 < nk) G_STAGE(buf ^ 1, kk + 1);
        short8 af[4], bfr[4];
#pragma unroll
        for (int mt = 0; mt < 4; ++mt)
            af[mt] = *(const short8*)&As[buf][lg][wr * 64 + mt * 16 + li][0];
#pragma unroll
        for (int nt = 0; nt < 4; ++nt)
            bfr[nt] = *(const short8*)&Bs[buf][lg][wc * 64 + nt * 16 + li][0];
#pragma unroll
        for (int mt = 0; mt < 4; ++mt)
#pragma unroll
            for (int nt = 0; nt < 4; ++nt)
                acc[mt][nt] = __builtin_amdgcn_mfma_f32_16x16x32_bf16(
                    af[mt], bfr[nt], acc[mt][nt], 0, 0, 0);
        __syncthreads();
        buf ^= 1;
    }
#undef G_STAGE

    // epilogue: C/D layout row=(l>>4)*4+r, col=l&15 per 16x16 tile
    if (WRITE_BF16) {
        ushort* C = (ushort*)Cout;
#pragma unroll
        for (int mt = 0; mt < 4; ++mt)
#pragma unroll
            for (int r = 0; r < 4; ++r) {
                int rg = row0 + wr * 64 + mt * 16 + lg * 4 + r;
#pragma unroll
                for (int nt = 0; nt < 4; ++nt)
                    C[(size_t)rg * N + col0 + wc * 64 + nt * 16 + li] =
                        f2bf(acc[mt][nt][r]);
            }
    } else {
        float* C = (float*)Cout;
#pragma unroll
        for (int mt = 0; mt < 4; ++mt)
#pragma unroll
            for (int r = 0; r < 4; ++r) {
                int rg = row0 + wr * 64 + mt * 16 + lg * 4 + r;
#pragma unroll
                for (int nt = 0; nt < 4; ++nt)
                    C[(size_t)rg * N + col0 + wc * 64 + nt * 16 + li] =
                        acc[mt][nt][r];
            }
    }
}

// ---------------- flash attention, bf16 MFMA ---------------------------------
// 4 waves, 64 q-rows/block (16 per wave), 64-key tiles.
// Q/K staged via global_load_lds into [g][row][16B]; V reg-transposed into
// [g_key][d][16B]; P per-wave in LDS [g_key][q][16B].
__global__ __launch_bounds__(256) void attn_mfma(const ushort* __restrict__ qkv,
                                                 ushort* __restrict__ o) {
    __shared__ __attribute__((aligned(16))) ushort Qs[8][64][8];
    __shared__ __attribute__((aligned(16))) ushort Ks[8][64][8];
    __shared__ __attribute__((aligned(16))) ushort Vt[8][64][8];
    __shared__ __attribute__((aligned(16))) ushort Ps[4][8][16][8];

    const int tid = threadIdx.x;
    const int l = tid & 63, li = l & 15, lg = l >> 4;
    const int w = tid >> 6;
    const int qt = gridDim.x - 1 - blockIdx.x;   // long blocks first
    const int hq = blockIdx.y, b = blockIdx.z, hk = hq >> 2;
    const int r0 = qt * 64;

    // stage Q once: 8 gload_lds over 4 waves
#pragma unroll
    for (int i = 0; i < 2; ++i) {
        int g = w + i * 4;
        gld16(qkv + (size_t)(b * Nseq + r0 + l) * QKVW + hq * 64 + g * 8,
              &Qs[g][0][0]);
    }

    f32x4 oacc[4];
    float mrow[4], lrow[4];
#pragma unroll
    for (int dt = 0; dt < 4; ++dt) {
        oacc[dt][0] = 0.f; oacc[dt][1] = 0.f; oacc[dt][2] = 0.f; oacc[dt][3] = 0.f;
    }
#pragma unroll
    for (int r = 0; r < 4; ++r) { mrow[r] = -INFINITY; lrow[r] = 0.f; }

    for (int t = 0; t <= qt; ++t) {
        const int s0 = t * 64;
        // stage K tile
#pragma unroll
        for (int i = 0; i < 2; ++i) {
            int g = w + i * 4;
            gld16(qkv + (size_t)(b * Nseq + s0 + l) * QKVW + 1024 + hk * 64 + g * 8,
                  &Ks[g][0][0]);
        }
        // stage V transposed: thread owns keys (kp,kp+1) x 8 d's
        {
            int kp = 2 * (tid & 31);
            int d0 = (tid >> 5) * 8;
            const ushort* vr =
                qkv + (size_t)(b * Nseq + s0 + kp) * QKVW + 1280 + hk * 64 + d0;
            short8 v0 = *(const short8*)vr;
            short8 v1 = *(const short8*)(vr + QKVW);
#pragma unroll
            for (int i2 = 0; i2 < 8; ++i2) {
                unsigned pv = ((unsigned)(unsigned short)v0[i2]) |
                              (((unsigned)(unsigned short)v1[i2]) << 16);
                ((unsigned*)Vt)[(kp >> 3) * 256 + (d0 + i2) * 4 + ((kp & 7) >> 1)] = pv;
            }
        }
        __syncthreads();

        // S = Q K^T  (wave w: q-rows w*16..+16, all 64 keys)
        f32x4 s[4];
#pragma unroll
        for (int kb = 0; kb < 4; ++kb) {
            s[kb][0] = 0.f; s[kb][1] = 0.f; s[kb][2] = 0.f; s[kb][3] = 0.f;
        }
#pragma unroll
        for (int c = 0; c < 2; ++c) {
            short8 aq = *(const short8*)&Qs[c * 4 + lg][w * 16 + li][0];
#pragma unroll
            for (int kb = 0; kb < 4; ++kb) {
                short8 bk = *(const short8*)&Ks[c * 4 + lg][kb * 16 + li][0];
                s[kb] = __builtin_amdgcn_mfma_f32_16x16x32_bf16(aq, bk, s[kb], 0, 0, 0);
            }
        }

        // scale + causal mask (only diagonal tile partial)
        const bool last = (t == qt);
#pragma unroll
        for (int kb = 0; kb < 4; ++kb)
#pragma unroll
            for (int r = 0; r < 4; ++r) {
                float v = s[kb][r] * 0.125f;
                if (last && (kb * 16 + li > w * 16 + lg * 4 + r)) v = -INFINITY;
                s[kb][r] = v;
            }

        // online softmax (rows live on 16-lane groups) + P -> LDS bf16
#pragma unroll
        for (int r = 0; r < 4; ++r) {
            float mx = fmaxf(fmaxf(s[0][r], s[1][r]), fmaxf(s[2][r], s[3][r]));
#pragma unroll
            for (int off = 1; off < 16; off <<= 1)
                mx = fmaxf(mx, __shfl_xor(mx, off, 64));
            float mn = fmaxf(mrow[r], mx);
            float al = __expf(mrow[r] - mn);
            float sum = 0.f;
#pragma unroll
            for (int kb = 0; kb < 4; ++kb) {
                float p = __expf(s[kb][r] - mn);
                s[kb][r] = p;
                sum += p;
            }
#pragma unroll
            for (int off = 1; off < 16; off <<= 1)
                sum += __shfl_xor(sum, off, 64);
            mrow[r] = mn;
            lrow[r] = lrow[r] * al + sum;
#pragma unroll
            for (int dt = 0; dt < 4; ++dt) oacc[dt][r] *= al;
#pragma unroll
            for (int kb = 0; kb < 4; ++kb)
                Ps[w][kb * 2 + (li >> 3)][lg * 4 + r][li & 7] = f2bf(s[kb][r]);
        }

        // O += P V   (same-wave P; LDS ops within a wave are in-order)
#pragma unroll
        for (int c = 0; c < 2; ++c) {
            short8 pa = *(const short8*)&Ps[w][c * 4 + lg][li][0];
#pragma unroll
            for (int dt = 0; dt < 4; ++dt) {
                short8 bv = *(const short8*)&Vt[c * 4 + lg][dt * 16 + li][0];
                oacc[dt] = __builtin_amdgcn_mfma_f32_16x16x32_bf16(pa, bv, oacc[dt], 0, 0, 0);
            }
        }
        __syncthreads();   // all reads done before next tile's staging
    }

    // epilogue: normalize, write bf16 at [row][hq*64+d]
#pragma unroll
    for (int r = 0; r < 4; ++r) {
        float inv = 1.0f / lrow[r];
        int rg = b * Nseq + r0 + w * 16 + lg * 4 + r;
#pragma unroll
        for (int dt = 0; dt < 4; ++dt)
            o[(size_t)rg * Edim + hq * 64 + dt * 16 + li] =
                f2bf(oacc[dt][r] * inv);
    }
}

// ---------------- launch ------------------------------------------------------
extern "C" void kernel_launch(void* const* d_in, const int* in_sizes, int n_in,
                              void* d_out, int out_size, void* d_ws, size_t ws_size,
                              hipStream_t stream) {
    const float* x  = (const float*)d_in[0];
    const float* Wq = (const float*)d_in[1];
    const float* Wk = (const float*)d_in[2];
    const float* Wv = (const float*)d_in[3];
    const float* Wo = (const float*)d_in[4];

    ushort* ws    = (ushort*)d_ws;
    ushort* xb    = ws;                          // 4096x1024
    ushort* WqkvT = xb + (size_t)ROWS * Edim;    // 1536x1024 (rows: WqT|WkT|WvT)
    ushort* WoT   = WqkvT + (size_t)QKVW * Edim; // 1024x1024
    ushort* qkv   = WoT + (size_t)Edim * Edim;   // 4096x1536 bf16
    ushort* at    = qkv + (size_t)ROWS * QKVW;   // 4096x1024 bf16

    castx<<<ROWS * Edim / (256 * 8), 256, 0, stream>>>(x, xb);
    tcast<<<dim3(32, 32), dim3(32, 8), 0, stream>>>(Wq, WqkvT, 1024, 1024);
    tcast<<<dim3(8, 32),  dim3(32, 8), 0, stream>>>(Wk, WqkvT + (size_t)1024 * 1024, 256, 1024);
    tcast<<<dim3(8, 32),  dim3(32, 8), 0, stream>>>(Wv, WqkvT + (size_t)1280 * 1024, 256, 1024);
    tcast<<<dim3(32, 32), dim3(32, 8), 0, stream>>>(Wo, WoT, 1024, 1024);

    gemm_bt<1><<<dim3(QKVW / 128, ROWS / 128), 256, 0, stream>>>(
        xb, WqkvT, qkv, ROWS, QKVW, Edim);

    attn_mfma<<<dim3(Nseq / 64, HQ, Bsz), 256, 0, stream>>>(qkv, at);

    gemm_bt<0><<<dim3(Edim / 128, ROWS / 128), 256, 0, stream>>>(
        at, WoT, d_out, ROWS, Edim, Edim);
}

// Round 4
// 288.625 us; speedup vs baseline: 4.1138x; 1.0211x over previous
//
#include <hip/hip_runtime.h>
#include <hip/hip_bf16.h>
#include <math.h>

// Problem constants
#define Bsz 2
#define Nseq 2048
#define Edim 1024
#define HQ 16
#define HK 4
#define Dh 64
#define ROWS (Bsz * Nseq)          // 4096
#define QKVW 1536                  // q(1024) | k(256) | v(256)
#define SCL 0.1803368801111244f    // 0.125 * log2(e)  (softmax in exp2 domain)

typedef __attribute__((ext_vector_type(8))) short short8;
typedef __attribute__((ext_vector_type(4))) float f32x4;

__device__ __forceinline__ ushort f2bf_u(float f) {
    union { __hip_bfloat16 h; ushort u; } c;
    c.h = __float2bfloat16(f);
    return c.u;
}
__device__ __forceinline__ unsigned bfpk(float lo, float hi) {
    return ((unsigned)f2bf_u(hi) << 16) | (unsigned)f2bf_u(lo);
}

// async global->LDS, 16B per lane; lds base must be wave-uniform
__device__ __forceinline__ void gld16(const void* g, void* l) {
    __builtin_amdgcn_global_load_lds(
        (const __attribute__((address_space(1))) unsigned*)g,
        (__attribute__((address_space(3))) unsigned*)l, 16, 0, 0);
}

// ---------------- prep: cast x to bf16 ---------------------------------------
__global__ __launch_bounds__(256) void castx(const float* __restrict__ x,
                                             ushort* __restrict__ xb) {
    size_t i = ((size_t)blockIdx.x * 256 + threadIdx.x) * 8;
    float4 a = *(const float4*)(x + i);
    float4 c = *(const float4*)(x + i + 4);
    short8 v;
    v[0] = f2bf_u(a.x); v[1] = f2bf_u(a.y); v[2] = f2bf_u(a.z); v[3] = f2bf_u(a.w);
    v[4] = f2bf_u(c.x); v[5] = f2bf_u(c.y); v[6] = f2bf_u(c.z); v[7] = f2bf_u(c.w);
    *(short8*)(xb + i) = v;
}

// ---------------- prep: transpose-cast W [K][N] fp32 -> WT [N][K] bf16 -------
__global__ __launch_bounds__(256) void tcast(const float* __restrict__ src,
                                             ushort* __restrict__ dst,
                                             int N, int Krows) {
    __shared__ float tle[32][33];
    int j0 = blockIdx.x * 32, k0 = blockIdx.y * 32;
    int tx = threadIdx.x, ty = threadIdx.y;
#pragma unroll
    for (int i = ty; i < 32; i += 8)
        tle[i][tx] = src[(size_t)(k0 + i) * N + j0 + tx];
    __syncthreads();
#pragma unroll
    for (int i = ty; i < 32; i += 8)
        dst[(size_t)(j0 + i) * Krows + k0 + tx] = f2bf_u(tle[tx][i]);
}

// ---------------- bf16 MFMA GEMM: C[M][N] = A[M][K] @ BT[N][K]^T -------------
template<int WRITE_BF16>
__global__ __launch_bounds__(256) void gemm_bt(const ushort* __restrict__ A,
                                               const ushort* __restrict__ BT,
                                               void* __restrict__ Cout,
                                               int M, int N, int K) {
    __shared__ __attribute__((aligned(16))) ushort As[2][4][128][8];
    __shared__ __attribute__((aligned(16))) ushort Bs[2][4][128][8];
    const int tid = threadIdx.x;
    const int l = tid & 63, li = l & 15, lg = l >> 4;
    const int w = tid >> 6;
    const int wr = w >> 1, wc = w & 1;
    const int row0 = blockIdx.y * 128, col0 = blockIdx.x * 128;

    f32x4 acc[4][4];
#pragma unroll
    for (int i = 0; i < 4; ++i)
#pragma unroll
        for (int j = 0; j < 4; ++j) {
            acc[i][j][0] = 0.f; acc[i][j][1] = 0.f;
            acc[i][j][2] = 0.f; acc[i][j][3] = 0.f;
        }

    const int nk = K >> 5;

#define G_STAGE(buf, kk)                                                        \
    {                                                                           \
        int k0 = (kk) << 5;                                                     \
        _Pragma("unroll")                                                       \
        for (int i = 0; i < 2; ++i) {                                           \
            int id = w + i * 4;                                                 \
            int g = id >> 1, h = id & 1;                                        \
            gld16(A + (size_t)(row0 + h * 64 + l) * K + k0 + g * 8,             \
                  &As[buf][g][h * 64][0]);                                      \
            gld16(BT + (size_t)(col0 + h * 64 + l) * K + k0 + g * 8,            \
                  &Bs[buf][g][h * 64][0]);                                      \
        }                                                                       \
    }

    G_STAGE(0, 0);
    __syncthreads();
    int buf = 0;
    for (int kk = 0; kk < nk; ++kk) {
        if (kk + 1 < nk) G_STAGE(buf ^ 1, kk + 1);
        short8 af[4], bfr[4];
#pragma unroll
        for (int mt = 0; mt < 4; ++mt)
            af[mt] = *(const short8*)&As[buf][lg][wr * 64 + mt * 16 + li][0];
#pragma unroll
        for (int nt = 0; nt < 4; ++nt)
            bfr[nt] = *(const short8*)&Bs[buf][lg][wc * 64 + nt * 16 + li][0];
#pragma unroll
        for (int mt = 0; mt < 4; ++mt)
#pragma unroll
            for (int nt = 0; nt < 4; ++nt)
                acc[mt][nt] = __builtin_amdgcn_mfma_f32_16x16x32_bf16(
                    af[mt], bfr[nt], acc[mt][nt], 0, 0, 0);
        __syncthreads();
        buf ^= 1;
    }
#undef G_STAGE

    if (WRITE_BF16) {
        ushort* C = (ushort*)Cout;
#pragma unroll
        for (int mt = 0; mt < 4; ++mt)
#pragma unroll
            for (int r = 0; r < 4; ++r) {
                int rg = row0 + wr * 64 + mt * 16 + lg * 4 + r;
#pragma unroll
                for (int nt = 0; nt < 4; ++nt)
                    C[(size_t)rg * N + col0 + wc * 64 + nt * 16 + li] =
                        f2bf_u(acc[mt][nt][r]);
            }
    } else {
        float* C = (float*)Cout;
#pragma unroll
        for (int mt = 0; mt < 4; ++mt)
#pragma unroll
            for (int r = 0; r < 4; ++r) {
                int rg = row0 + wr * 64 + mt * 16 + lg * 4 + r;
#pragma unroll
                for (int nt = 0; nt < 4; ++nt)
                    C[(size_t)rg * N + col0 + wc * 64 + nt * 16 + li] =
                        acc[mt][nt][r];
            }
    }
}

// ---------------- flash attention, bf16 MFMA, swapped-QK^T softmax -----------
// 4 waves, 64 q-rows/block (16 per wave). S^T = mfma(K,Q): lane owns q-row
// li, 16 keys. Softmax fully per-lane + 2 shuffles. P packed to LDS as b64.
// Vt XOR-swizzled (col ^= g<<2) so transpose-writes are conflict-free.
__global__ __launch_bounds__(256) void attn_mfma(const ushort* __restrict__ qkv,
                                                 ushort* __restrict__ o) {
    __shared__ __attribute__((aligned(16))) ushort Qs[8][64][8];
    __shared__ __attribute__((aligned(16))) ushort Ks[8][64][8];
    __shared__ __attribute__((aligned(16))) ushort Vt[8][64][8];
    __shared__ __attribute__((aligned(16))) ushort Ps[4][8][16][8];

    const int tid = threadIdx.x;
    const int l = tid & 63, li = l & 15, lg = l >> 4;
    const int w = tid >> 6;
    const int qt = gridDim.x - 1 - blockIdx.x;   // long blocks first
    const int hq = blockIdx.y, b = blockIdx.z, hk = hq >> 2;
    const int r0 = qt * 64;

    // stage Q once
#pragma unroll
    for (int i = 0; i < 2; ++i) {
        int g = w + i * 4;
        gld16(qkv + (size_t)(b * Nseq + r0 + l) * QKVW + hq * 64 + g * 8,
              &Qs[g][0][0]);
    }
    __syncthreads();
    short8 q8[2];
    q8[0] = *(const short8*)&Qs[lg][w * 16 + li][0];
    q8[1] = *(const short8*)&Qs[4 + lg][w * 16 + li][0];

    f32x4 oacc[4];
#pragma unroll
    for (int dt = 0; dt < 4; ++dt) {
        oacc[dt][0] = 0.f; oacc[dt][1] = 0.f; oacc[dt][2] = 0.f; oacc[dt][3] = 0.f;
    }
    float m = -INFINITY, lsum = 0.f;
    const int qloc = w * 16 + li;   // this lane's q-row (local to tile)

    unsigned* VtD = (unsigned*)Vt;

    for (int t = 0; t <= qt; ++t) {
        const int s0 = t * 64;
        // stage K tile
#pragma unroll
        for (int i = 0; i < 2; ++i) {
            int g = w + i * 4;
            gld16(qkv + (size_t)(b * Nseq + s0 + l) * QKVW + 1024 + hk * 64 + g * 8,
                  &Ks[g][0][0]);
        }
        // stage V transposed + swizzled: thread owns keys (kp,kp+1) x 8 d's
        {
            int kp = 2 * (tid & 31);
            int d0 = (tid >> 5) * 8;
            int g = kp >> 3, pr = (kp & 7) >> 1;
            const ushort* vr =
                qkv + (size_t)(b * Nseq + s0 + kp) * QKVW + 1280 + hk * 64 + d0;
            short8 v0 = *(const short8*)vr;
            short8 v1 = *(const short8*)(vr + QKVW);
#pragma unroll
            for (int i2 = 0; i2 < 8; ++i2) {
                unsigned pv = ((unsigned)(unsigned short)v0[i2]) |
                              (((unsigned)(unsigned short)v1[i2]) << 16);
                VtD[g * 256 + ((((d0 + i2) * 4) + pr) ^ (g << 2))] = pv;
            }
        }
        __syncthreads();

        // S^T = K Q  (swapped: lane holds col=q-row li, rows=keys lg*4+r+16kb)
        f32x4 s[4];
#pragma unroll
        for (int kb = 0; kb < 4; ++kb) {
            s[kb][0] = 0.f; s[kb][1] = 0.f; s[kb][2] = 0.f; s[kb][3] = 0.f;
        }
#pragma unroll
        for (int c = 0; c < 2; ++c) {
#pragma unroll
            for (int kb = 0; kb < 4; ++kb) {
                short8 bk = *(const short8*)&Ks[c * 4 + lg][kb * 16 + li][0];
                s[kb] = __builtin_amdgcn_mfma_f32_16x16x32_bf16(bk, q8[c], s[kb], 0, 0, 0);
            }
        }

        // scale (exp2 domain) + causal mask; p[] = this lane's 16 keys
        float p[16];
        const bool last = (t == qt);
#pragma unroll
        for (int kb = 0; kb < 4; ++kb)
#pragma unroll
            for (int r = 0; r < 4; ++r) {
                float sv = s[kb][r] * SCL;
                if (last && (kb * 16 + lg * 4 + r > qloc)) sv = -INFINITY;
                p[kb * 4 + r] = sv;
            }

        // per-lane softmax over own 16 + 2 cross-lg shuffles
        float mx = p[0];
#pragma unroll
        for (int i = 1; i < 16; ++i) mx = fmaxf(mx, p[i]);
        mx = fmaxf(mx, __shfl_xor(mx, 16, 64));
        mx = fmaxf(mx, __shfl_xor(mx, 32, 64));
        float mn = fmaxf(m, mx);
        float al = exp2f(m - mn);           // first tile: exp2(-inf)=0
        float sum = 0.f;
#pragma unroll
        for (int i = 0; i < 16; ++i) {
            float e = exp2f(p[i] - mn);
            p[i] = e;
            sum += e;
        }
        sum += __shfl_xor(sum, 16, 64);
        sum += __shfl_xor(sum, 32, 64);
        m = mn;
        lsum = lsum * al + sum;

        // rescale O: alpha for q-row lg*4+r comes from lane lg*4+r
        float alr[4];
#pragma unroll
        for (int r = 0; r < 4; ++r) alr[r] = __shfl(al, lg * 4 + r, 64);
#pragma unroll
        for (int dt = 0; dt < 4; ++dt)
#pragma unroll
            for (int r = 0; r < 4; ++r) oacc[dt][r] *= alr[r];

        // pack P -> LDS: keys kb*16+lg*4+{0..3} are 4 consecutive ushorts
#pragma unroll
        for (int kb = 0; kb < 4; ++kb) {
            unsigned lo = bfpk(p[kb * 4 + 0], p[kb * 4 + 1]);
            unsigned hi = bfpk(p[kb * 4 + 2], p[kb * 4 + 3]);
            *(unsigned long long*)&Ps[w][2 * kb + (lg >> 1)][li][(lg & 1) * 4] =
                ((unsigned long long)hi << 32) | (unsigned long long)lo;
        }

        // O += P V
#pragma unroll
        for (int c = 0; c < 2; ++c) {
            short8 pa = *(const short8*)&Ps[w][c * 4 + lg][li][0];
#pragma unroll
            for (int dt = 0; dt < 4; ++dt) {
                int g = c * 4 + lg, d = dt * 16 + li;
                short8 bv = *(const short8*)(VtD + g * 256 + ((d * 4) ^ (g << 2)));
                oacc[dt] = __builtin_amdgcn_mfma_f32_16x16x32_bf16(pa, bv, oacc[dt], 0, 0, 0);
            }
        }
        __syncthreads();   // all reads done before next tile's staging
    }

    // epilogue: 1/l for q-row lg*4+r from lane lg*4+r
    float linv[4];
#pragma unroll
    for (int r = 0; r < 4; ++r) linv[r] = 1.0f / __shfl(lsum, lg * 4 + r, 64);
#pragma unroll
    for (int r = 0; r < 4; ++r) {
        int rg = b * Nseq + r0 + w * 16 + lg * 4 + r;
#pragma unroll
        for (int dt = 0; dt < 4; ++dt)
            o[(size_t)rg * Edim + hq * 64 + dt * 16 + li] =
                f2bf_u(oacc[dt][r] * linv[r]);
    }
}

// ---------------- launch ------------------------------------------------------
extern "C" void kernel_launch(void* const* d_in, const int* in_sizes, int n_in,
                              void* d_out, int out_size, void* d_ws, size_t ws_size,
                              hipStream_t stream) {
    const float* x  = (const float*)d_in[0];
    const float* Wq = (const float*)d_in[1];
    const float* Wk = (const float*)d_in[2];
    const float* Wv = (const float*)d_in[3];
    const float* Wo = (const float*)d_in[4];

    ushort* ws    = (ushort*)d_ws;
    ushort* xb    = ws;                          // 4096x1024
    ushort* WqkvT = xb + (size_t)ROWS * Edim;    // 1536x1024 (rows: WqT|WkT|WvT)
    ushort* WoT   = WqkvT + (size_t)QKVW * Edim; // 1024x1024
    ushort* qkv   = WoT + (size_t)Edim * Edim;   // 4096x1536 bf16
    ushort* at    = qkv + (size_t)ROWS * QKVW;   // 4096x1024 bf16

    castx<<<ROWS * Edim / (256 * 8), 256, 0, stream>>>(x, xb);
    tcast<<<dim3(32, 32), dim3(32, 8), 0, stream>>>(Wq, WqkvT, 1024, 1024);
    tcast<<<dim3(8, 32),  dim3(32, 8), 0, stream>>>(Wk, WqkvT + (size_t)1024 * 1024, 256, 1024);
    tcast<<<dim3(8, 32),  dim3(32, 8), 0, stream>>>(Wv, WqkvT + (size_t)1280 * 1024, 256, 1024);
    tcast<<<dim3(32, 32), dim3(32, 8), 0, stream>>>(Wo, WoT, 1024, 1024);

    gemm_bt<1><<<dim3(QKVW / 128, ROWS / 128), 256, 0, stream>>>(
        xb, WqkvT, qkv, ROWS, QKVW, Edim);

    attn_mfma<<<dim3(Nseq / 64, HQ, Bsz), 256, 0, stream>>>(qkv, at);

    gemm_bt<0><<<dim3(Edim / 128, ROWS / 128), 256, 0, stream>>>(
        at, WoT, d_out, ROWS, Edim, Edim);
}

// Round 6
// 260.058 us; speedup vs baseline: 4.5657x; 1.1098x over previous
//
#include <hip/hip_runtime.h>
#include <hip/hip_bf16.h>
#include <math.h>

// Problem constants
#define Bsz 2
#define Nseq 2048
#define Edim 1024
#define HQ 16
#define HK 4
#define Dh 64
#define ROWS (Bsz * Nseq)          // 4096
#define QKVW 1536                  // q(1024) | k(256) | v(256)
#define SCL 0.1803368801111244f    // 0.125 * log2(e)  (softmax in exp2 domain)

typedef __attribute__((ext_vector_type(8))) short short8;
typedef __attribute__((ext_vector_type(4))) float f32x4;

__device__ __forceinline__ ushort f2bf_u(float f) {
    union { __hip_bfloat16 h; ushort u; } c;
    c.h = __float2bfloat16(f);
    return c.u;
}
__device__ __forceinline__ unsigned bfpk(float lo, float hi) {
    return ((unsigned)f2bf_u(hi) << 16) | (unsigned)f2bf_u(lo);
}

// async global->LDS, 16B per lane; lds base must be wave-uniform
__device__ __forceinline__ void gld16(const void* g, void* l) {
    __builtin_amdgcn_global_load_lds(
        (const __attribute__((address_space(1))) unsigned*)g,
        (__attribute__((address_space(3))) unsigned*)l, 16, 0, 0);
}

// ---------------- prep: cast x to bf16 ---------------------------------------
__global__ __launch_bounds__(256) void castx(const float* __restrict__ x,
                                             ushort* __restrict__ xb) {
    size_t i = ((size_t)blockIdx.x * 256 + threadIdx.x) * 8;
    float4 a = *(const float4*)(x + i);
    float4 c = *(const float4*)(x + i + 4);
    short8 v;
    v[0] = f2bf_u(a.x); v[1] = f2bf_u(a.y); v[2] = f2bf_u(a.z); v[3] = f2bf_u(a.w);
    v[4] = f2bf_u(c.x); v[5] = f2bf_u(c.y); v[6] = f2bf_u(c.z); v[7] = f2bf_u(c.w);
    *(short8*)(xb + i) = v;
}

// ---------------- prep: transpose-cast W [K][N] fp32 -> WT [N][K] bf16 -------
__global__ __launch_bounds__(256) void tcast(const float* __restrict__ src,
                                             ushort* __restrict__ dst,
                                             int N, int Krows) {
    __shared__ float tle[32][33];
    int j0 = blockIdx.x * 32, k0 = blockIdx.y * 32;
    int tx = threadIdx.x, ty = threadIdx.y;
#pragma unroll
    for (int i = ty; i < 32; i += 8)
        tle[i][tx] = src[(size_t)(k0 + i) * N + j0 + tx];
    __syncthreads();
#pragma unroll
    for (int i = ty; i < 32; i += 8)
        dst[(size_t)(j0 + i) * Krows + k0 + tx] = f2bf_u(tle[tx][i]);
}

// ---------------- bf16 MFMA GEMM: C[M][N] = A[M][K] @ BT[N][K]^T -------------
template<int WRITE_BF16>
__global__ __launch_bounds__(256) void gemm_bt(const ushort* __restrict__ A,
                                               const ushort* __restrict__ BT,
                                               void* __restrict__ Cout,
                                               int M, int N, int K) {
    __shared__ __attribute__((aligned(16))) ushort As[2][4][128][8];
    __shared__ __attribute__((aligned(16))) ushort Bs[2][4][128][8];
    const int tid = threadIdx.x;
    const int l = tid & 63, li = l & 15, lg = l >> 4;
    const int w = tid >> 6;
    const int wr = w >> 1, wc = w & 1;
    const int row0 = blockIdx.y * 128, col0 = blockIdx.x * 128;

    f32x4 acc[4][4];
#pragma unroll
    for (int i = 0; i < 4; ++i)
#pragma unroll
        for (int j = 0; j < 4; ++j) {
            acc[i][j][0] = 0.f; acc[i][j][1] = 0.f;
            acc[i][j][2] = 0.f; acc[i][j][3] = 0.f;
        }

    const int nk = K >> 5;

#define G_STAGE(buf, kk)                                                        \
    {                                                                           \
        int k0 = (kk) << 5;                                                     \
        _Pragma("unroll")                                                       \
        for (int i = 0; i < 2; ++i) {                                           \
            int id = w + i * 4;                                                 \
            int g = id >> 1, h = id & 1;                                        \
            gld16(A + (size_t)(row0 + h * 64 + l) * K + k0 + g * 8,             \
                  &As[buf][g][h * 64][0]);                                      \
            gld16(BT + (size_t)(col0 + h * 64 + l) * K + k0 + g * 8,            \
                  &Bs[buf][g][h * 64][0]);                                      \
        }                                                                       \
    }

    G_STAGE(0, 0);
    __syncthreads();
    int buf = 0;
    for (int kk = 0; kk < nk; ++kk) {
        if (kk + 1 < nk) G_STAGE(buf ^ 1, kk + 1);
        short8 af[4], bfr[4];
#pragma unroll
        for (int mt = 0; mt < 4; ++mt)
            af[mt] = *(const short8*)&As[buf][lg][wr * 64 + mt * 16 + li][0];
#pragma unroll
        for (int nt = 0; nt < 4; ++nt)
            bfr[nt] = *(const short8*)&Bs[buf][lg][wc * 64 + nt * 16 + li][0];
#pragma unroll
        for (int mt = 0; mt < 4; ++mt)
#pragma unroll
            for (int nt = 0; nt < 4; ++nt)
                acc[mt][nt] = __builtin_amdgcn_mfma_f32_16x16x32_bf16(
                    af[mt], bfr[nt], acc[mt][nt], 0, 0, 0);
        __syncthreads();
        buf ^= 1;
    }
#undef G_STAGE

    if (WRITE_BF16) {
        ushort* C = (ushort*)Cout;
#pragma unroll
        for (int mt = 0; mt < 4; ++mt)
#pragma unroll
            for (int r = 0; r < 4; ++r) {
                int rg = row0 + wr * 64 + mt * 16 + lg * 4 + r;
#pragma unroll
                for (int nt = 0; nt < 4; ++nt)
                    C[(size_t)rg * N + col0 + wc * 64 + nt * 16 + li] =
                        f2bf_u(acc[mt][nt][r]);
            }
    } else {
        float* C = (float*)Cout;
#pragma unroll
        for (int mt = 0; mt < 4; ++mt)
#pragma unroll
            for (int r = 0; r < 4; ++r) {
                int rg = row0 + wr * 64 + mt * 16 + lg * 4 + r;
#pragma unroll
                for (int nt = 0; nt < 4; ++nt)
                    C[(size_t)rg * N + col0 + wc * 64 + nt * 16 + li] =
                        acc[mt][nt][r];
            }
    }
}

// ---------------- flash attention, bf16 MFMA, 2-phase pipelined --------------
// 4 waves, 64 q-rows/block. Double-buffered K (gld_lds) and V (reg-staged,
// T14 split: issue loads at iter top, LDS-write before the single barrier).
// Softmax per-lane via swapped QK^T. Ps aliases dead Qs LDS (40KB total).
__global__ __launch_bounds__(256) void attn_mfma(const ushort* __restrict__ qkv,
                                                 ushort* __restrict__ o) {
    __shared__ __attribute__((aligned(16))) char smem[40960];
    ushort (*Ks)[8][64][8]  = (ushort (*)[8][64][8])smem;            // [2] x 8KB
    unsigned* VtD           = (unsigned*)(smem + 16384);             // [2] x 8KB
    ushort (*Qs)[64][8]     = (ushort (*)[64][8])(smem + 32768);     // 8KB
    ushort (*Ps)[8][16][8]  = (ushort (*)[8][16][8])(smem + 32768);  // alias Qs

    const int tid = threadIdx.x;
    const int l = tid & 63, li = l & 15, lg = l >> 4;
    const int w = tid >> 6;
    const int qt = gridDim.x - 1 - blockIdx.x;   // long blocks first
    const int hq = blockIdx.y, b = blockIdx.z, hk = hq >> 2;
    const int r0 = qt * 64;

    // V-stage lane mapping: thread owns keys (kp,kp+1) x 8 d's
    const int kp = 2 * (tid & 31), d0v = (tid >> 5) * 8;
    const int gv = kp >> 3, prv = (kp & 7) >> 1;

    // ---- prologue: issue Q + K(0) stages and V(0) reg loads -----------------
#pragma unroll
    for (int i = 0; i < 2; ++i) {
        int g = w + i * 4;
        gld16(qkv + (size_t)(b * Nseq + r0 + l) * QKVW + hq * 64 + g * 8,
              &Qs[g][0][0]);
        gld16(qkv + (size_t)(b * Nseq + l) * QKVW + 1024 + hk * 64 + g * 8,
              &Ks[0][g][0][0]);
    }
    const ushort* vr0 = qkv + (size_t)(b * Nseq + kp) * QKVW + 1280 + hk * 64 + d0v;
    short8 va = *(const short8*)vr0;
    short8 vb = *(const short8*)(vr0 + QKVW);
    __syncthreads();                      // Q,K(0) in LDS; V(0) regs pending
    short8 q8[2];
    q8[0] = *(const short8*)&Qs[lg][w * 16 + li][0];
    q8[1] = *(const short8*)&Qs[4 + lg][w * 16 + li][0];
#pragma unroll
    for (int i2 = 0; i2 < 8; ++i2) {
        unsigned pv = ((unsigned)(unsigned short)va[i2]) |
                      (((unsigned)(unsigned short)vb[i2]) << 16);
        VtD[gv * 256 + (((d0v + i2) * 4 + prv) ^ (gv << 2))] = pv;
    }
    __syncthreads();                      // V(0) visible; Qs dead -> Ps live

    f32x4 oacc[4];
#pragma unroll
    for (int dt = 0; dt < 4; ++dt) {
        oacc[dt][0] = 0.f; oacc[dt][1] = 0.f; oacc[dt][2] = 0.f; oacc[dt][3] = 0.f;
    }
    float m = -INFINITY, lsum = 0.f;
    const int qloc = w * 16 + li;         // this lane's q-row (local to tile)

    // ---- main loop: one barrier per key-tile --------------------------------
    for (int t = 0; t <= qt; ++t) {
        const int cur = t & 1, nxt = cur ^ 1;
        const bool pre = (t < qt);
        short8 vna, vnb;
        if (pre) {                        // issue next tile's loads FIRST
            const int s1 = (t + 1) * 64;
#pragma unroll
            for (int i = 0; i < 2; ++i) {
                int g = w + i * 4;
                gld16(qkv + (size_t)(b * Nseq + s1 + l) * QKVW + 1024 + hk * 64 + g * 8,
                      &Ks[nxt][g][0][0]);
            }
            const ushort* vr =
                qkv + (size_t)(b * Nseq + s1 + kp) * QKVW + 1280 + hk * 64 + d0v;
            vna = *(const short8*)vr;
            vnb = *(const short8*)(vr + QKVW);
        }

        // S^T = K Q  (swapped: lane holds q-row li, keys kb*16+lg*4+r)
        f32x4 s[4];
#pragma unroll
        for (int kb = 0; kb < 4; ++kb) {
            s[kb][0] = 0.f; s[kb][1] = 0.f; s[kb][2] = 0.f; s[kb][3] = 0.f;
        }
#pragma unroll
        for (int c = 0; c < 2; ++c) {
#pragma unroll
            for (int kb = 0; kb < 4; ++kb) {
                short8 bk = *(const short8*)&Ks[cur][c * 4 + lg][kb * 16 + li][0];
                s[kb] = __builtin_amdgcn_mfma_f32_16x16x32_bf16(bk, q8[c], s[kb], 0, 0, 0);
            }
        }

        // scale (exp2 domain) + causal mask
        float p[16];
        const bool last = (t == qt);
#pragma unroll
        for (int kb = 0; kb < 4; ++kb)
#pragma unroll
            for (int r = 0; r < 4; ++r) {
                float sv = s[kb][r] * SCL;
                if (last && (kb * 16 + lg * 4 + r > qloc)) sv = -INFINITY;
                p[kb * 4 + r] = sv;
            }

        // per-lane softmax over own 16 + 2 cross-lg shuffles
        float mx = p[0];
#pragma unroll
        for (int i = 1; i < 16; ++i) mx = fmaxf(mx, p[i]);
        mx = fmaxf(mx, __shfl_xor(mx, 16, 64));
        mx = fmaxf(mx, __shfl_xor(mx, 32, 64));
        float mn = fmaxf(m, mx);
        float al = exp2f(m - mn);         // first tile: exp2(-inf)=0
        float sum = 0.f;
#pragma unroll
        for (int i = 0; i < 16; ++i) {
            float e = exp2f(p[i] - mn);
            p[i] = e;
            sum += e;
        }
        sum += __shfl_xor(sum, 16, 64);
        sum += __shfl_xor(sum, 32, 64);
        m = mn;
        lsum = lsum * al + sum;

        // rescale O: alpha for q-row lg*4+r comes from lane lg*4+r
        float alr[4];
#pragma unroll
        for (int r = 0; r < 4; ++r) alr[r] = __shfl(al, lg * 4 + r, 64);
#pragma unroll
        for (int dt = 0; dt < 4; ++dt)
#pragma unroll
            for (int r = 0; r < 4; ++r) oacc[dt][r] *= alr[r];

        // pack P -> LDS (b64 per kb)
#pragma unroll
        for (int kb = 0; kb < 4; ++kb) {
            unsigned lo = bfpk(p[kb * 4 + 0], p[kb * 4 + 1]);
            unsigned hi = bfpk(p[kb * 4 + 2], p[kb * 4 + 3]);
            *(unsigned long long*)&Ps[w][2 * kb + (lg >> 1)][li][(lg & 1) * 4] =
                ((unsigned long long)hi << 32) | (unsigned long long)lo;
        }

        // write V(t+1) regs -> LDS (waits its global loads; overlapped w/ above)
        if (pre) {
#pragma unroll
            for (int i2 = 0; i2 < 8; ++i2) {
                unsigned pv = ((unsigned)(unsigned short)vna[i2]) |
                              (((unsigned)(unsigned short)vnb[i2]) << 16);
                VtD[nxt * 2048 + gv * 256 + (((d0v + i2) * 4 + prv) ^ (gv << 2))] = pv;
            }
        }

        // O += P V  (same-wave P; wave-ordered LDS)
#pragma unroll
        for (int c = 0; c < 2; ++c) {
            short8 pa = *(const short8*)&Ps[w][c * 4 + lg][li][0];
#pragma unroll
            for (int dt = 0; dt < 4; ++dt) {
                int g = c * 4 + lg, d = dt * 16 + li;
                short8 bv = *(const short8*)(VtD + cur * 2048 + g * 256 + ((d * 4) ^ (g << 2)));
                oacc[dt] = __builtin_amdgcn_mfma_f32_16x16x32_bf16(pa, bv, oacc[dt], 0, 0, 0);
            }
        }
        __syncthreads();   // drains K(t+1) gld16 + V writes; cur reads done
    }

    // epilogue: 1/l for q-row lg*4+r from lane lg*4+r
    float linv[4];
#pragma unroll
    for (int r = 0; r < 4; ++r) linv[r] = 1.0f / __shfl(lsum, lg * 4 + r, 64);
#pragma unroll
    for (int r = 0; r < 4; ++r) {
        int rg = b * Nseq + r0 + w * 16 + lg * 4 + r;
#pragma unroll
        for (int dt = 0; dt < 4; ++dt)
            o[(size_t)rg * Edim + hq * 64 + dt * 16 + li] =
                f2bf_u(oacc[dt][r] * linv[r]);
    }
}

// ---------------- launch ------------------------------------------------------
extern "C" void kernel_launch(void* const* d_in, const int* in_sizes, int n_in,
                              void* d_out, int out_size, void* d_ws, size_t ws_size,
                              hipStream_t stream) {
    const float* x  = (const float*)d_in[0];
    const float* Wq = (const float*)d_in[1];
    const float* Wk = (const float*)d_in[2];
    const float* Wv = (const float*)d_in[3];
    const float* Wo = (const float*)d_in[4];

    ushort* ws    = (ushort*)d_ws;
    ushort* xb    = ws;                          // 4096x1024
    ushort* WqkvT = xb + (size_t)ROWS * Edim;    // 1536x1024 (rows: WqT|WkT|WvT)
    ushort* WoT   = WqkvT + (size_t)QKVW * Edim; // 1024x1024
    ushort* qkv   = WoT + (size_t)Edim * Edim;   // 4096x1536 bf16
    ushort* at    = qkv + (size_t)ROWS * QKVW;   // 4096x1024 bf16

    castx<<<ROWS * Edim / (256 * 8), 256, 0, stream>>>(x, xb);
    tcast<<<dim3(32, 32), dim3(32, 8), 0, stream>>>(Wq, WqkvT, 1024, 1024);
    tcast<<<dim3(8, 32),  dim3(32, 8), 0, stream>>>(Wk, WqkvT + (size_t)1024 * 1024, 256, 1024);
    tcast<<<dim3(8, 32),  dim3(32, 8), 0, stream>>>(Wv, WqkvT + (size_t)1280 * 1024, 256, 1024);
    tcast<<<dim3(32, 32), dim3(32, 8), 0, stream>>>(Wo, WoT, 1024, 1024);

    gemm_bt<1><<<dim3(QKVW / 128, ROWS / 128), 256, 0, stream>>>(
        xb, WqkvT, qkv, ROWS, QKVW, Edim);

    attn_mfma<<<dim3(Nseq / 64, HQ, Bsz), 256, 0, stream>>>(qkv, at);

    gemm_bt<0><<<dim3(Edim / 128, ROWS / 128), 256, 0, stream>>>(
        at, WoT, d_out, ROWS, Edim, Edim);
}